// Round 1
// 113.750 us; speedup vs baseline: 1.0157x; 1.0157x over previous
//
#include <hip/hip_runtime.h>
#include <math.h>

typedef __attribute__((ext_vector_type(8))) short bf16x8;
typedef __attribute__((ext_vector_type(4))) float f32x4;

#define MFMA(a, b, c) __builtin_amdgcn_mfma_f32_16x16x32_bf16(a, b, c, 0, 0, 0)

constexpr int GN = 128;   // B*T
constexpr int NN = 512;   // nodes
constexpr int FD = 128;   // F_in == D == 128
#define LOG2E 1.4426950408889634f

// round-to-nearest-even bf16 kept in the TOP 16 bits of a u32
__device__ inline unsigned rne_top16(float x) {
    unsigned u = __float_as_uint(x);
    return u + 0x7fffu + ((u >> 16) & 1u);
}
// pack top-16 of e0 (-> low half) and e1 (-> high half)
__device__ inline unsigned pack_top16(unsigned e1, unsigned e0) {
    return __builtin_amdgcn_perm(e1, e0, 0x07060302u);
}
// async global->LDS, 16 bytes per lane
__device__ inline void gload16(const void* g, void* l) {
    __builtin_amdgcn_global_load_lds(
        (const __attribute__((address_space(1))) unsigned*)g,
        (__attribute__((address_space(3))) unsigned*)l, 16, 0, 0);
}

// ---------------------------------------------------------------------------
// whb: block (g, jt): Wh rows jt*128..+128 = h@W via 3-split bf16 MFMA.
// prep is FUSED here:
//   - W is loaded fp32 (64 KB, L2-resident after first block) and split to
//     hi(trunc)/lo(rne) bf16 in-register, written to LDS in the MFMA-B
//     swizzle: elem (k,d) -> pos ((kk*8+nb)*64+lane)*8+idx,
//     kk=k>>5, nb=d>>4, lane=(d&15)+16*((k>>3)&3), idx=k&7.
//   - adjacency bitmask row `bid` built via two __ballot over 512 entries.
// h loads issue into registers before everything; K-loop barrier-free.
// Outputs: esrc/edst fp32; WhT as SINGLE RNE bf16 in global B-fragment
// swizzle (elem (j,d) of g at g*65536 + ((KK*8+nb)*64+lanep)*8+idx,
// KK=j>>5, nb=d>>4, lanep=(d&15)+16*((j>>3)&3), idx=j&7).
// ---------------------------------------------------------------------------
__global__ __launch_bounds__(256, 2) void whb_kernel(
    const float* __restrict__ h, const float* __restrict__ a,
    const int* __restrict__ adj, const float* __restrict__ W,
    unsigned short* __restrict__ whtHi,
    float* __restrict__ esrc, float* __restrict__ edst,
    unsigned* __restrict__ mask)
{
    __shared__ __attribute__((aligned(16))) unsigned short sW[32768]; // 64 KB

    const int bid = blockIdx.x;
    const int xcd = bid & 7, slot = bid >> 3;
    const int g = xcd + 8 * (slot >> 2);
    const int jt = slot & 3;
    const int t = threadIdx.x, lane = t & 63, w = t >> 6;
    const int i0r = jt * 128;
    const int q8 = (lane >> 4) * 8;
    const float* hg = h + (size_t)(g * NN) * FD;

    // issue all h loads first (registers) — the HBM stream everything hides under
    float4 hv[16];
    #pragma unroll
    for (int kk = 0; kk < 4; ++kk)
        #pragma unroll
        for (int mt = 0; mt < 2; ++mt) {
            const float* src = hg + (size_t)(i0r + w * 32 + mt * 16 + (lane & 15)) * FD
                             + kk * 32 + q8;
            hv[(kk * 2 + mt) * 2 + 0] = *(const float4*)src;
            hv[(kk * 2 + mt) * 2 + 1] = *(const float4*)(src + 4);
        }

    // ---- fused prep (a): adjacency bitmask, one row per block ----
    {
        const int pred0 = adj[bid * NN + t] > 0;
        const int pred1 = adj[bid * NN + 256 + t] > 0;
        const unsigned long long m0 = __ballot(pred0);
        const unsigned long long m1 = __ballot(pred1);
        if (lane == 0) {
            mask[bid * 16 + 2 * w]     = (unsigned)m0;
            mask[bid * 16 + 8 + 2 * w] = (unsigned)m1;
        } else if (lane == 1) {
            mask[bid * 16 + 2 * w + 1]     = (unsigned)(m0 >> 32);
            mask[bid * 16 + 8 + 2 * w + 1] = (unsigned)(m1 >> 32);
        }
    }

    // ---- fused prep (b): W fp32 -> hi/lo bf16 split, swizzled into LDS ----
    #pragma unroll
    for (int grp = 0; grp < 8; ++grp) {
        const int p8 = grp * 256 + t;              // 0..2047 (covers pos=p8*8..+7)
        const int lanep = p8 & 63, cn = p8 >> 6;   // cn 0..31
        const int kks = cn >> 3, nbs = cn & 7;
        const int kbase = kks * 32 + ((lanep >> 4) & 3) * 8;
        const int d = nbs * 16 + (lanep & 15);
        unsigned hi[8], lo[8];
        #pragma unroll
        for (int idx = 0; idx < 8; ++idx) {
            const float wv = W[(kbase + idx) * FD + d];
            const unsigned u = __float_as_uint(wv);
            hi[idx] = u;                            // top16 = truncation
            lo[idx] = rne_top16(wv - __uint_as_float(u & 0xffff0000u));
        }
        uint4 H4, L4;
        H4.x = pack_top16(hi[1], hi[0]); H4.y = pack_top16(hi[3], hi[2]);
        H4.z = pack_top16(hi[5], hi[4]); H4.w = pack_top16(hi[7], hi[6]);
        L4.x = pack_top16(lo[1], lo[0]); L4.y = pack_top16(lo[3], lo[2]);
        L4.z = pack_top16(lo[5], lo[4]); L4.w = pack_top16(lo[7], lo[6]);
        *(uint4*)&sW[p8 * 8]         = H4;
        *(uint4*)&sW[16384 + p8 * 8] = L4;
    }
    __syncthreads();

    f32x4 acc[2][8];
    #pragma unroll
    for (int mt = 0; mt < 2; ++mt)
        #pragma unroll
        for (int nb = 0; nb < 8; ++nb) acc[mt][nb] = (f32x4){0.f, 0.f, 0.f, 0.f};

    #pragma unroll
    for (int kk = 0; kk < 4; ++kk) {
        bf16x8 ah[2], al[2];
        #pragma unroll
        for (int mt = 0; mt < 2; ++mt) {
            const float4 f0 = hv[(kk * 2 + mt) * 2 + 0];
            const float4 f1 = hv[(kk * 2 + mt) * 2 + 1];
            const float xs[8] = {f0.x, f0.y, f0.z, f0.w, f1.x, f1.y, f1.z, f1.w};
            union { bf16x8 v; unsigned u[4]; } H, L;
            #pragma unroll
            for (int j = 0; j < 4; ++j) {
                const unsigned e0 = __float_as_uint(xs[2 * j]);
                const unsigned e1 = __float_as_uint(xs[2 * j + 1]);
                H.u[j] = pack_top16(e1, e0);
                const unsigned l0 = rne_top16(xs[2*j]   - __uint_as_float(e0 & 0xffff0000u));
                const unsigned l1 = rne_top16(xs[2*j+1] - __uint_as_float(e1 & 0xffff0000u));
                L.u[j] = pack_top16(l1, l0);
            }
            ah[mt] = H.v; al[mt] = L.v;
        }
        #pragma unroll
        for (int nb = 0; nb < 8; ++nb) {
            const bf16x8 bh = *(const bf16x8*)&sW[((kk * 8 + nb) * 64 + lane) * 8];
            const bf16x8 bl = *(const bf16x8*)&sW[16384 + ((kk * 8 + nb) * 64 + lane) * 8];
            #pragma unroll
            for (int mt = 0; mt < 2; ++mt) {
                acc[mt][nb] = MFMA(al[mt], bh, acc[mt][nb]);
                acc[mt][nb] = MFMA(ah[mt], bl, acc[mt][nb]);
                acc[mt][nb] = MFMA(ah[mt], bh, acc[mt][nb]);
            }
        }
    }

    // ---- esrc / edst: per-row dot with a_src / a_dst, reduce over 16 lanes ----
    float av[8], bv[8];
    #pragma unroll
    for (int nb = 0; nb < 8; ++nb) {
        av[nb] = a[nb * 16 + (lane & 15)];
        bv[nb] = a[FD + nb * 16 + (lane & 15)];
    }
    #pragma unroll
    for (int mt = 0; mt < 2; ++mt)
        #pragma unroll
        for (int r = 0; r < 4; ++r) {
            float ps = 0.f, pd = 0.f;
            #pragma unroll
            for (int nb = 0; nb < 8; ++nb) {
                ps += acc[mt][nb][r] * av[nb];
                pd += acc[mt][nb][r] * bv[nb];
            }
            #pragma unroll
            for (int off = 1; off <= 8; off <<= 1) {
                ps += __shfl_xor(ps, off);
                pd += __shfl_xor(pd, off);
            }
            if ((lane & 15) == 0) {
                const int row = g * NN + i0r + w * 32 + mt * 16 + (lane >> 4) * 4 + r;
                esrc[row] = ps;
                edst[row] = pd;
            }
        }

    // ---- transpose Wh -> swizzled single RNE bf16, ONE pass (reuse sW) ----
    unsigned short* sT = sW;             // 16384 shorts (32 KB)
    const size_t gbase = (size_t)g * 65536 + (size_t)jt * 16384;
    const int ib = 4 * ((lane >> 4) & 1);

    __syncthreads();                     // everyone done reading sW
    #pragma unroll
    for (int mt = 0; mt < 2; ++mt) {
        const int lp2 = (lane & 15) + 16 * (mt * 2 + (lane >> 5));
        #pragma unroll
        for (int nb = 0; nb < 8; ++nb) {
            const int off = ((w * 8 + nb) * 64 + lp2) * 8 + ib;
            const unsigned r0 = rne_top16(acc[mt][nb][0]);
            const unsigned r1 = rne_top16(acc[mt][nb][1]);
            const unsigned r2 = rne_top16(acc[mt][nb][2]);
            const unsigned r3 = rne_top16(acc[mt][nb][3]);
            *(uint2*)&sT[off] = make_uint2(pack_top16(r1, r0), pack_top16(r3, r2));
        }
    }
    __syncthreads();
    for (int q = t; q < 2048; q += 256)
        *(float4*)&whtHi[gbase + q * 8] = *(const float4*)&sT[q * 8];
}

// ---------------------------------------------------------------------------
// attn: block (g, it): 128 rows (2 row-tiles/wave), grid 512 (2 blocks/CU —
// r7 showed 1 block/CU exposes the chunk barrier; keep 2). B operand is
// SINGLE bf16 Wh. No max-subtraction (shift-invariant; masked -> p = 0
// exactly). lsum now comes from MFMA against a register-constant "ones
// column" B fragment (lane&15==0 holds bf16 1.0): the row-sums of exactly
// the truncated-bf16 P the PV MFMAs consume — truncation common-mode
// cancellation preserved, and the per-element AND + lsum-add + final
// shfl_xor reductions are deleted (~13% of attn VALU).
// Double-buffered 16 KB chunks via global_load_lds; mask LDS stride 17.
// LDS = 32 + 2 + 8.5 ~ 42.5 KB.
// ---------------------------------------------------------------------------
__global__ __launch_bounds__(256, 2) void attn_kernel(
    const unsigned short* __restrict__ whtHi,
    const float* __restrict__ esrc, const float* __restrict__ edst,
    const unsigned* __restrict__ mask, float* __restrict__ out)
{
    __shared__ __attribute__((aligned(16))) float eds[NN];              // 2 KB
    __shared__ unsigned maskS[128 * 17];                                // 8.5 KB
    __shared__ __attribute__((aligned(16))) unsigned short cHi[2][8192];// 32 KB

    const int bid = blockIdx.x;
    const int xcd = bid & 7, slot = bid >> 3;
    const int g = xcd + 8 * (slot >> 2);
    const int it = slot & 3;
    const int t = threadIdx.x, lane = t & 63, w = t >> 6;
    const int i0 = it * 128;
    const int q8 = (lane >> 4) * 8;
    const int l15 = lane & 15;

    eds[t]       = edst[g * NN + t] * LOG2E;
    eds[t + 256] = edst[g * NN + 256 + t] * LOG2E;
    for (int q = t; q < 2048; q += 256) {        // 128 rows x 16 words
        const int row = q >> 4, wo = q & 15;
        maskS[row * 17 + wo] = mask[(i0 + row) * 16 + wo];
    }

    const int rloc0 = w * 32 + l15;              // local row in [0,128)
    const int rloc1 = rloc0 + 16;
    const float s0 = esrc[g * NN + i0 + rloc0] * LOG2E;
    const float s1 = esrc[g * NN + i0 + rloc1] * LOG2E;

    // register-constant B fragment: ones in column 0 (lane&15==0), else 0
    union { bf16x8 v; unsigned short s[8]; } bo;
    {
        const unsigned short oneb = (l15 == 0) ? (unsigned short)0x3f80 : (unsigned short)0;
        #pragma unroll
        for (int j = 0; j < 8; ++j) bo.s[j] = oneb;
    }

    // stage chunk 0 into buffer 0 (chunk = 64 j-rows = 8192 shorts)
    const size_t gbase = (size_t)g * 65536;
    for (int q = t; q < 1024; q += 256)
        gload16(&whtHi[gbase + q * 8], &cHi[0][q * 8]);
    __syncthreads();   // covers eds/maskS writes + chunk-0 staging

    f32x4 acc[2][8];
    #pragma unroll
    for (int mt = 0; mt < 2; ++mt)
        #pragma unroll
        for (int nb = 0; nb < 8; ++nb) acc[mt][nb] = (f32x4){0.f, 0.f, 0.f, 0.f};
    f32x4 accS0 = (f32x4){0.f, 0.f, 0.f, 0.f};
    f32x4 accS1 = (f32x4){0.f, 0.f, 0.f, 0.f};

    for (int c2 = 0; c2 < 8; ++c2) {
        const int cur = c2 & 1, nxt = cur ^ 1;
        if (c2 < 7) {                              // prefetch next chunk
            const size_t gb = gbase + (size_t)(c2 + 1) * 8192;
            for (int q = t; q < 1024; q += 256)
                gload16(&whtHi[gb + q * 8], &cHi[nxt][q * 8]);
        }
        const unsigned short* __restrict__ bHi = &cHi[cur][0];
        #pragma unroll
        for (int kl = 0; kl < 2; ++kl) {
            const int kk = c2 * 2 + kl;
            const float* ep = &eds[kk * 32 + q8];
            const float4 ed0 = *(const float4*)ep;
            const float4 ed1 = *(const float4*)(ep + 4);
            const float ev[8] = {ed0.x, ed0.y, ed0.z, ed0.w, ed1.x, ed1.y, ed1.z, ed1.w};
            const unsigned mw0 = maskS[rloc0 * 17 + kk] >> q8;
            const unsigned mw1 = maskS[rloc1 * 17 + kk] >> q8;

            union { bf16x8 v; unsigned u[4]; } H0, H1;
            unsigned uh0[8], uh1[8];
            #pragma unroll
            for (int i = 0; i < 8; ++i) {
                const float z0 = s0 + ev[i];
                float p0 = __builtin_amdgcn_exp2f(fmaxf(z0, 0.2f * z0));
                p0 = ((mw0 >> i) & 1u) ? p0 : 0.f;
                uh0[i] = __float_as_uint(p0);
                const float z1 = s1 + ev[i];
                float p1 = __builtin_amdgcn_exp2f(fmaxf(z1, 0.2f * z1));
                p1 = ((mw1 >> i) & 1u) ? p1 : 0.f;
                uh1[i] = __float_as_uint(p1);
            }
            #pragma unroll
            for (int j = 0; j < 4; ++j) {
                H0.u[j] = pack_top16(uh0[2*j+1], uh0[2*j]);   // perm keeps top16 = trunc
                H1.u[j] = pack_top16(uh1[2*j+1], uh1[2*j]);
            }
            #pragma unroll
            for (int nb = 0; nb < 8; ++nb) {
                const bf16x8 bh = *(const bf16x8*)&bHi[((kl * 8 + nb) * 64 + lane) * 8];
                acc[0][nb] = MFMA(H0.v, bh, acc[0][nb]);
                acc[1][nb] = MFMA(H1.v, bh, acc[1][nb]);
            }
            accS0 = MFMA(H0.v, bo.v, accS0);       // row-sums (lsum) in column 0
            accS1 = MFMA(H1.v, bo.v, accS1);
        }
        __syncthreads();   // all waves done with cur; prefetch into nxt landed
    }

    #pragma unroll
    for (int r = 0; r < 4; ++r) {
        // lsum for this lane's output row rr=(lane>>4)*4+r sits at
        // lane (rr>>2)*16 == (lane & 48), register r, column 0
        const float rl0 = 1.0f / __shfl(accS0[r], lane & 48);
        const float rl1 = 1.0f / __shfl(accS1[r], lane & 48);
        const int row0 = g * NN + i0 + w * 32 + (lane >> 4) * 4 + r;
        const int row1 = row0 + 16;
        #pragma unroll
        for (int nb = 0; nb < 8; ++nb) {
            out[row0 * FD + nb * 16 + l15] = acc[0][nb][r] * rl0;
            out[row1 * FD + nb * 16 + l15] = acc[1][nb][r] * rl1;
        }
    }
}

// ---------------------------------------------------------------------------
extern "C" void kernel_launch(void* const* d_in, const int* in_sizes, int n_in,
                              void* d_out, int out_size, void* d_ws, size_t ws_size,
                              hipStream_t stream) {
    const float* h   = (const float*)d_in[0];
    const int*   adj = (const int*)d_in[1];
    const float* W   = (const float*)d_in[2];
    const float* a   = (const float*)d_in[3];
    float* out = (float*)d_out;

    unsigned short* whtHi = (unsigned short*)d_ws;                       // 16.78 MB
    float* esrc = (float*)(whtHi + (size_t)GN * 65536);                  // 256 KB
    float* edst = esrc + GN * NN;                                        // 256 KB
    unsigned* mask = (unsigned*)(edst + GN * NN);                        // 32 KB

    whb_kernel<<<512, 256, 0, stream>>>(h, a, adj, W, whtHi, esrc, edst, mask);
    attn_kernel<<<512, 256, 0, stream>>>(whtHi, esrc, edst, mask, out);
}